// Round 1
// baseline (1022.322 us; speedup 1.0000x reference)
//
#include <hip/hip_runtime.h>
#include <hip/hip_cooperative_groups.h>

namespace cg = cooperative_groups;

#define N_NODES  100000
#define N_EDGES  3200000
#define N_FEAT   512
#define N_GRAPHS 64
#define N_COLS   516
#define NBINS    1563            // ceil(N_NODES / 64), 64 nodes per bin
#define B1       256             // histogram column blocks
#define EPB      (N_EDGES / B1)  // 12500 edges per block chunk
#define CHUNK    25              // rows per wave in the fused x pass
#define NWAVES   (N_NODES / CHUNK)  // 4000, exact
#define SRC_MASK 0x1FFFF
#define GRID_B   1024            // layers kernel blocks (4/CU, co-resident)

// ---------------------------------------------------------------------------
// colsum flush: wave-private partial per-graph colsum -> per-wave slot (fast
// path, <=2 graph segments per 25-row chunk) or atomics to out (rare overflow).
// ---------------------------------------------------------------------------
__device__ __forceinline__ void flush_cs(
    int si, int cur_g, const float a[8], int wave, int lane,
    float* __restrict__ pp, int* __restrict__ pt, float* __restrict__ out)
{
    if (si < 2) {
        const int slot = wave * 2 + si;
        if (lane == 0) pt[slot] = cur_g;
        float* d = pp + (size_t)slot * N_FEAT + lane * 8;
        *(float4*)d       = make_float4(a[0], a[1], a[2], a[3]);
        *(float4*)(d + 4) = make_float4(a[4], a[5], a[6], a[7]);
    } else {
        float* o = out + (size_t)cur_g * N_COLS + lane * 8;
        #pragma unroll
        for (int k = 0; k < 8; ++k) atomicAdd(o + k, a[k]);
    }
}

// ---------------------------------------------------------------------------
// K1 (cooperative, 256 x 1024): entire prep + sort + x-pass pipeline.
//   phase 0: zero out[], graph starts, per-block dst-bin histogram
//   phase A: wave-per-bin column scan (no barriers)  ||  fused x pass
//   phase B: single-wave scan of bin totals -> binstart
//   phase C: reorder edges into dst-bin-sorted order
// ---------------------------------------------------------------------------
__global__ __launch_bounds__(1024) void mega_prep_kernel(
    const float* __restrict__ x, const int* __restrict__ esrc,
    const int* __restrict__ edst, const int* __restrict__ gid,
    const float* __restrict__ wn, const float* __restrict__ ws,
    float* __restrict__ p0, float* __restrict__ s0,
    float* __restrict__ out, float* __restrict__ pp, int* __restrict__ pt,
    int* __restrict__ histG, int* __restrict__ colscanG, int* __restrict__ totalG,
    int* __restrict__ starts, int* __restrict__ binstart, int* __restrict__ sorted)
{
    __shared__ int lh[NBINS];   // phase 0: histogram; phase C: running offsets
    cg::grid_group grid = cg::this_grid();
    const int b = blockIdx.x, tid = threadIdx.x;
    const int gtid = b * 1024 + tid;

    // ---- phase 0 -----------------------------------------------------------
    if (gtid < N_GRAPHS * N_COLS) out[gtid] = 0.f;
    if (gtid < N_NODES) {
        const int g = gid[gtid];
        const int gp = gtid ? gid[gtid - 1] : -1;
        for (int q = gp + 1; q <= g; ++q) starts[q] = gtid;
        if (gtid == N_NODES - 1)
            for (int q = g + 1; q <= N_GRAPHS; ++q) starts[q] = N_NODES;
    }
    for (int i = tid; i < NBINS; i += 1024) lh[i] = 0;
    __syncthreads();
    {
        const int e0 = b * EPB;
        for (int e = e0 + tid; e < e0 + EPB; e += 1024)
            atomicAdd(&lh[edst[e] >> 6], 1);
    }
    __syncthreads();
    for (int i = tid; i < NBINS; i += 1024) histG[i * B1 + b] = lh[i];

    grid.sync();

    // ---- phase A: column scans (1563 waves) + x pass (4000 waves) ----------
    const int gwave = gtid >> 6;
    const int lane = tid & 63;

    if (gwave < NBINS) {
        const int4 v = *(const int4*)(histG + (size_t)gwave * B1 + lane * 4);
        const int s1 = v.x, s2 = s1 + v.y, s3 = s2 + v.z;
        const int tot = s3 + v.w;
        int incl = tot;
        #pragma unroll
        for (int off = 1; off < 64; off <<= 1) {
            const int t = __shfl_up(incl, off);
            if (lane >= off) incl += t;
        }
        const int excl = incl - tot;
        *(int4*)(colscanG + (size_t)gwave * B1 + lane * 4) =
            make_int4(excl, excl + s1, excl + s2, excl + s3);
        if (lane == 63) totalG[gwave] = incl;
    }

    if (gwave < NWAVES) {
        const int start = gwave * CHUNK, end = start + CHUNK;   // exact fit

        const float4 wna = *(const float4*)(wn + lane * 8);
        const float4 wnb = *(const float4*)(wn + lane * 8 + 4);
        const float4 wsa = *(const float4*)(ws + lane * 8);
        const float4 wsb = *(const float4*)(ws + lane * 8 + 4);

        float a[8] = {0.f, 0.f, 0.f, 0.f, 0.f, 0.f, 0.f, 0.f};
        int cur_g = gid[start];
        const bool uniform = (gid[end - 1] == cur_g);
        int si = 0;

        for (int n = start; n < end; ++n) {
            if (!uniform) {
                const int g = gid[n];
                if (g != cur_g) {
                    flush_cs(si, cur_g, a, gwave, lane, pp, pt, out);
                    ++si;
                    #pragma unroll
                    for (int k = 0; k < 8; ++k) a[k] = 0.f;
                    cur_g = g;
                }
            }
            const float* row = x + (size_t)n * N_FEAT;
            const float4 xa = *(const float4*)(row + lane * 8);
            const float4 xb = *(const float4*)(row + lane * 8 + 4);

            a[0] += xa.x; a[1] += xa.y; a[2] += xa.z; a[3] += xa.w;
            a[4] += xb.x; a[5] += xb.y; a[6] += xb.z; a[7] += xb.w;

            float dn = xa.x*wna.x + xa.y*wna.y + xa.z*wna.z + xa.w*wna.w
                     + xb.x*wnb.x + xb.y*wnb.y + xb.z*wnb.z + xb.w*wnb.w;
            float dv = xa.x*wsa.x + xa.y*wsa.y + xa.z*wsa.z + xa.w*wsa.w
                     + xb.x*wsb.x + xb.y*wsb.y + xb.z*wsb.z + xb.w*wsb.w;
            #pragma unroll
            for (int off = 32; off > 0; off >>= 1) {
                dn += __shfl_down(dn, off);
                dv += __shfl_down(dv, off);
            }
            if (lane == 0) { p0[n] = dn; s0[n] = dv; }
        }
        flush_cs(si, cur_g, a, gwave, lane, pp, pt, out);
        ++si;
        if (lane == 0)
            for (int s2i = si; s2i < 2; ++s2i) pt[gwave * 2 + s2i] = -1;
    }

    grid.sync();

    // ---- phase B: bin-total scan -> binstart (one wave, no barriers) -------
    if (b == 0 && tid < 64) {
        int loc[25];
        int s = 0;
        #pragma unroll
        for (int i = 0; i < 25; ++i) {
            const int bin = tid * 25 + i;
            loc[i] = s;
            s += (bin < NBINS) ? totalG[bin] : 0;
        }
        int incl = s;
        #pragma unroll
        for (int off = 1; off < 64; off <<= 1) {
            const int t = __shfl_up(incl, off);
            if (tid >= off) incl += t;
        }
        const int excl = incl - s;
        #pragma unroll
        for (int i = 0; i < 25; ++i) {
            const int bin = tid * 25 + i;
            if (bin <= NBINS) binstart[bin] = excl + loc[i];
        }
    }

    grid.sync();

    // ---- phase C: reorder --------------------------------------------------
    for (int i = tid; i < NBINS; i += 1024)
        lh[i] = binstart[i] + colscanG[i * B1 + b];
    __syncthreads();
    {
        const int e0 = b * EPB;
        for (int e = e0 + tid; e < e0 + EPB; e += 1024) {
            const int s = esrc[e], d = edst[e];
            const int p = atomicAdd(&lh[d >> 6], 1);
            sorted[p] = s | ((d & 63) << 17);
        }
    }
}

// ---------------------------------------------------------------------------
// One GraphConv layer over this block's bins: LDS-accumulated neighbor sum,
// fused node update + per-graph reduction (~1 global atomic per bin).
// ---------------------------------------------------------------------------
__device__ __forceinline__ void scatter_layer(
    const int* __restrict__ sorted, const int* __restrict__ binstart,
    const float* __restrict__ pin, const float* __restrict__ self_in,
    const float* __restrict__ wself_p, const float* __restrict__ bias_p,
    const float* __restrict__ wnext_p,
    float* __restrict__ h_out, float* __restrict__ p_next,
    const int* __restrict__ gid, float* __restrict__ out, int col,
    float (*acc)[64])
{
    const int tid = threadIdx.x;
    const float sw    = wself_p ? *wself_p : 1.0f;
    const float bias  = *bias_p;
    const float wnext = wnext_p ? *wnext_p : 0.0f;

    for (int b = blockIdx.x; b < NBINS; b += GRID_B) {
        ((float*)acc)[tid] = 0.f;
        __syncthreads();
        const int st = binstart[b], en = binstart[b + 1];
        const int w = tid >> 6;
        for (int e = st + tid; e < en; e += 256) {
            const int v = sorted[e];
            atomicAdd(&acc[w][v >> 17], pin[v & SRC_MASK]);
        }
        __syncthreads();
        if (tid < 64) {
            const int n = b * 64 + tid;
            const bool valid = (n < N_NODES);
            float h = 0.f;
            int g = 0;
            if (valid) {
                const float nb = acc[0][tid] + acc[1][tid] + acc[2][tid] + acc[3][tid];
                const float v = nb + bias + sw * self_in[n];
                h = v > 0.f ? v : 0.f;
                h_out[n] = h;
                if (wnext_p) p_next[n] = h * wnext;
                g = gid[n];
            }
            const int g0 = __shfl(g, 0);
            if (__all(!valid || g == g0)) {
                float sacc = h;
                #pragma unroll
                for (int off = 32; off > 0; off >>= 1) sacc += __shfl_down(sacc, off);
                if (tid == 0) atomicAdd(&out[(size_t)g0 * N_COLS + col], sacc);
            } else if (valid) {
                atomicAdd(&out[(size_t)g * N_COLS + col], h);
            }
        }
        __syncthreads();
    }
}

// ---------------------------------------------------------------------------
// K2 (cooperative, 1024 x 256): reduce_x (folded into layer-0 phase on blocks
// 960..1023, which own only one bin) + all 4 conv layers, grid.sync between.
// Blocks own the same bins every layer -> sorted slice is L2-hot on layers 1-3.
// ---------------------------------------------------------------------------
__global__ __launch_bounds__(256) void layers_kernel(
    const int* __restrict__ sorted, const int* __restrict__ binstart,
    const int* __restrict__ gid, float* __restrict__ out,
    float* __restrict__ bufP, float* __restrict__ bufS,
    float* __restrict__ bufP2, float* __restrict__ bufH,
    const float* __restrict__ b0p, const float* __restrict__ Wnr,
    const float* __restrict__ Wsr, const float* __restrict__ brp,
    const float* __restrict__ pp, const int* __restrict__ pt,
    const int* __restrict__ starts)
{
    __shared__ float acc[4][64];
    cg::grid_group grid = cg::this_grid();

    // fold per-wave colsum partials into out[:, 0:512] (disjoint from col 512+)
    if (blockIdx.x >= GRID_B - N_GRAPHS) {
        const int g = blockIdx.x - (GRID_B - N_GRAPHS);
        const int s = starts[g], e = starts[g + 1];
        for (int c = threadIdx.x; c < N_FEAT; c += 256) {
            float accv = 0.f;
            if (e > s) {
                const int w0 = s / CHUNK, w1 = (e - 1) / CHUNK;
                for (int w = w0; w <= w1; ++w) {
                    #pragma unroll
                    for (int k = 0; k < 2; ++k) {
                        const int slot = w * 2 + k;
                        if (pt[slot] == g) accv += pp[(size_t)slot * N_FEAT + c];
                    }
                }
            }
            out[(size_t)g * N_COLS + c] += accv;
        }
    }

    scatter_layer(sorted, binstart, bufP,  bufS, nullptr, b0p,     Wnr + 0, bufH, bufP2, gid, out, 512, acc);
    grid.sync();
    scatter_layer(sorted, binstart, bufP2, bufH, Wsr + 0, brp + 0, Wnr + 1, bufH, bufP,  gid, out, 513, acc);
    grid.sync();
    scatter_layer(sorted, binstart, bufP,  bufH, Wsr + 1, brp + 1, Wnr + 2, bufH, bufP2, gid, out, 514, acc);
    grid.sync();
    scatter_layer(sorted, binstart, bufP2, bufH, Wsr + 2, brp + 2, nullptr, bufH, nullptr, gid, out, 515, acc);
}

extern "C" void kernel_launch(void* const* d_in, const int* in_sizes, int n_in,
                              void* d_out, int out_size, void* d_ws, size_t ws_size,
                              hipStream_t stream)
{
    (void)in_sizes; (void)n_in; (void)out_size; (void)ws_size;

    const float* x    = (const float*)d_in[0];
    const int*   esrc = (const int*)d_in[1];
    const int*   edst = (const int*)d_in[2];
    const int*   gid  = (const int*)d_in[3];
    const float* Wn0  = (const float*)d_in[4];
    const float* Ws0  = (const float*)d_in[5];
    const float* b0p  = (const float*)d_in[6];
    const float* Wnr  = (const float*)d_in[7];
    const float* Wsr  = (const float*)d_in[8];
    const float* brp  = (const float*)d_in[9];
    float* out = (float*)d_out;

    // workspace layout (16B-aligned throughout; int arrays padded to x4)
    float* pp    = (float*)d_ws;                         // NWAVES*2*512 floats
    float* bufP  = pp + (size_t)NWAVES * 2 * N_FEAT;
    float* bufP2 = bufP  + N_NODES;
    float* bufS  = bufP2 + N_NODES;
    float* bufH  = bufS  + N_NODES;
    int*   pt       = (int*)(bufH + N_NODES);            // NWAVES*2 = 8000
    int*   starts   = pt + NWAVES * 2;                   // 65 -> pad to 68
    int*   binstart = starts + 68;                       // NBINS+1 = 1564
    int*   totalG   = binstart + 1564;                   // NBINS -> pad 1564
    int*   histG    = totalG + 1564;                     // NBINS*B1
    int*   colscanG = histG + (size_t)NBINS * B1;        // NBINS*B1
    int*   sorted   = colscanG + (size_t)NBINS * B1;     // N_EDGES

    {
        void* args[] = {
            (void*)&x, (void*)&esrc, (void*)&edst, (void*)&gid,
            (void*)&Wn0, (void*)&Ws0, (void*)&bufP, (void*)&bufS,
            (void*)&out, (void*)&pp, (void*)&pt,
            (void*)&histG, (void*)&colscanG, (void*)&totalG,
            (void*)&starts, (void*)&binstart, (void*)&sorted
        };
        hipLaunchCooperativeKernel((const void*)mega_prep_kernel,
                                   dim3(B1), dim3(1024), args, 0, stream);
    }
    {
        void* args[] = {
            (void*)&sorted, (void*)&binstart, (void*)&gid, (void*)&out,
            (void*)&bufP, (void*)&bufS, (void*)&bufP2, (void*)&bufH,
            (void*)&b0p, (void*)&Wnr, (void*)&Wsr, (void*)&brp,
            (void*)&pp, (void*)&pt, (void*)&starts
        };
        hipLaunchCooperativeKernel((const void*)layers_kernel,
                                   dim3(GRID_B), dim3(256), args, 0, stream);
    }
}

// Round 2
// 512.494 us; speedup vs baseline: 1.9948x; 1.9948x over previous
//
#include <hip/hip_runtime.h>

#define N_NODES  100000
#define N_EDGES  3200000
#define N_FEAT   512
#define N_GRAPHS 64
#define N_COLS   516
#define NBINS    1563            // ceil(N_NODES / 64), 64 nodes per bin
#define B1       256             // histogram column blocks
#define EPB      (N_EDGES / B1)  // 12500 edges per block chunk
#define CHUNK    25              // rows per wave in the fused x pass
#define NWAVES   (N_NODES / CHUNK)  // 4000, exact
#define SRC_MASK 0x1FFFF

// ---------------------------------------------------------------------------
// K1 prep: zero out[], find graph starts, per-block edge histogram.
// grid = B1 x 1024.
// ---------------------------------------------------------------------------
__global__ __launch_bounds__(1024) void prep_kernel(
    const int* __restrict__ edst, const int* __restrict__ gid,
    int* __restrict__ histG, int* __restrict__ starts, float* __restrict__ outz)
{
    __shared__ int lh[NBINS];
    const int b = blockIdx.x, tid = threadIdx.x;
    const int gtid = b * 1024 + tid;

    if (gtid < N_GRAPHS * N_COLS) outz[gtid] = 0.f;
    if (gtid < N_NODES) {
        const int g = gid[gtid];
        const int gp = gtid ? gid[gtid - 1] : -1;
        for (int q = gp + 1; q <= g; ++q) starts[q] = gtid;
        if (gtid == N_NODES - 1)
            for (int q = g + 1; q <= N_GRAPHS; ++q) starts[q] = N_NODES;
    }
    for (int i = tid; i < NBINS; i += 1024) lh[i] = 0;
    __syncthreads();
    const int e0 = b * EPB;
    for (int e = e0 + tid; e < e0 + EPB; e += 1024)
        atomicAdd(&lh[edst[e] >> 6], 1);
    __syncthreads();
    for (int i = tid; i < NBINS; i += 1024) histG[i * B1 + b] = lh[i];
}

// ---------------------------------------------------------------------------
// K2 fused x pass: one read of x computes
//   p0[n]=x.Wn, s0[n]=x.Ws (wave-per-row, shuffle reduce)
//   per-graph colsum partials (registers, flushed to per-wave slots; no atomics)
// Wave w owns rows [25w, 25w+25). Lane l owns cols [8l, 8l+8).
// ---------------------------------------------------------------------------
__device__ __forceinline__ void flush_cs(
    int si, int cur_g, const float a[8], int wave, int lane,
    float* __restrict__ pp, int* __restrict__ pt, float* __restrict__ out)
{
    if (si < 2) {
        const int slot = wave * 2 + si;
        if (lane == 0) pt[slot] = cur_g;
        float* d = pp + (size_t)slot * N_FEAT + lane * 8;
        *(float4*)d       = make_float4(a[0], a[1], a[2], a[3]);
        *(float4*)(d + 4) = make_float4(a[4], a[5], a[6], a[7]);
    } else {
        float* o = out + (size_t)cur_g * N_COLS + lane * 8;
        #pragma unroll
        for (int k = 0; k < 8; ++k) atomicAdd(o + k, a[k]);
    }
}

__global__ __launch_bounds__(256) void pass_x_kernel(
    const float* __restrict__ x, const int* __restrict__ gid,
    const float* __restrict__ wn, const float* __restrict__ ws,
    float* __restrict__ p0, float* __restrict__ s0,
    float* __restrict__ out,
    float* __restrict__ pp, int* __restrict__ pt)
{
    const int wave = (blockIdx.x * blockDim.x + threadIdx.x) >> 6;
    const int lane = threadIdx.x & 63;
    const int start = wave * CHUNK, end = start + CHUNK;   // exact fit

    const float4 wna = *(const float4*)(wn + lane * 8);
    const float4 wnb = *(const float4*)(wn + lane * 8 + 4);
    const float4 wsa = *(const float4*)(ws + lane * 8);
    const float4 wsb = *(const float4*)(ws + lane * 8 + 4);

    float a[8] = {0.f, 0.f, 0.f, 0.f, 0.f, 0.f, 0.f, 0.f};
    int cur_g = gid[start];
    const bool uniform = (gid[end - 1] == cur_g);
    int si = 0;

    for (int n = start; n < end; ++n) {
        if (!uniform) {
            const int g = gid[n];
            if (g != cur_g) {
                flush_cs(si, cur_g, a, wave, lane, pp, pt, out);
                ++si;
                #pragma unroll
                for (int k = 0; k < 8; ++k) a[k] = 0.f;
                cur_g = g;
            }
        }
        const float* row = x + (size_t)n * N_FEAT;
        const float4 xa = *(const float4*)(row + lane * 8);
        const float4 xb = *(const float4*)(row + lane * 8 + 4);

        a[0] += xa.x; a[1] += xa.y; a[2] += xa.z; a[3] += xa.w;
        a[4] += xb.x; a[5] += xb.y; a[6] += xb.z; a[7] += xb.w;

        float dn = xa.x*wna.x + xa.y*wna.y + xa.z*wna.z + xa.w*wna.w
                 + xb.x*wnb.x + xb.y*wnb.y + xb.z*wnb.z + xb.w*wnb.w;
        float dv = xa.x*wsa.x + xa.y*wsa.y + xa.z*wsa.z + xa.w*wsa.w
                 + xb.x*wsb.x + xb.y*wsb.y + xb.z*wsb.z + xb.w*wsb.w;
        #pragma unroll
        for (int off = 32; off > 0; off >>= 1) {
            dn += __shfl_down(dn, off);
            dv += __shfl_down(dv, off);
        }
        if (lane == 0) { p0[n] = dn; s0[n] = dv; }
    }
    flush_cs(si, cur_g, a, wave, lane, pp, pt, out);
    ++si;
    if (lane == 0)
        for (int s2 = si; s2 < 2; ++s2) pt[wave * 2 + s2] = -1;  // unused slots
}

// K6: fold per-wave colsum partials into out (graph g's slots live in a
// contiguous wave range). out already holds zero + rare overflow atomics.
__global__ __launch_bounds__(512) void reduce_x_kernel(
    const float* __restrict__ pp, const int* __restrict__ pt,
    const int* __restrict__ starts, float* __restrict__ out)
{
    const int g = blockIdx.x, c = threadIdx.x;
    const int s = starts[g], e = starts[g + 1];
    float acc = 0.f;
    if (e > s) {
        const int w0 = s / CHUNK, w1 = (e - 1) / CHUNK;
        for (int w = w0; w <= w1; ++w) {
            #pragma unroll
            for (int k = 0; k < 2; ++k) {
                const int slot = w * 2 + k;
                if (pt[slot] == g) acc += pp[(size_t)slot * N_FEAT + c];
            }
        }
    }
    out[(size_t)g * N_COLS + c] += acc;
}

// ---------------------------------------------------------------------------
// Sort pipeline (counting sort by dst bin = dst >> 6).
// ---------------------------------------------------------------------------
__global__ __launch_bounds__(256) void colscan_kernel(
    const int* __restrict__ histG, int* __restrict__ colscanG,
    int* __restrict__ totalG)
{
    __shared__ int sc[256];
    const int bin = blockIdx.x, t = threadIdx.x;
    const int v = histG[bin * B1 + t];
    sc[t] = v;
    __syncthreads();
    for (int off = 1; off < 256; off <<= 1) {
        const int a = (t >= off) ? sc[t - off] : 0;
        __syncthreads();
        sc[t] += a;
        __syncthreads();
    }
    colscanG[bin * B1 + t] = sc[t] - v;
    if (t == 255) totalG[bin] = sc[255];
}

__global__ __launch_bounds__(256) void scan2_kernel(
    const int* __restrict__ totalG, int* __restrict__ binstart)
{
    __shared__ int sc[256];
    const int t = threadIdx.x;
    const int CH = 7;
    int loc[CH];
    int s = 0;
    for (int i = 0; i < CH; ++i) {
        const int bin = t * CH + i;
        const int v = (bin < NBINS) ? totalG[bin] : 0;
        loc[i] = s; s += v;
    }
    const int my = s;
    sc[t] = my;
    __syncthreads();
    for (int off = 1; off < 256; off <<= 1) {
        const int a = (t >= off) ? sc[t - off] : 0;
        __syncthreads();
        sc[t] += a;
        __syncthreads();
    }
    const int texcl = sc[t] - my;
    for (int i = 0; i < CH; ++i) {
        const int bin = t * CH + i;
        if (bin < NBINS) binstart[bin] = texcl + loc[i];
    }
    if (t == 255) binstart[NBINS] = sc[255];
}

__global__ __launch_bounds__(1024) void reorder_kernel(
    const int* __restrict__ esrc, const int* __restrict__ edst,
    const int* __restrict__ binstart, const int* __restrict__ colscanG,
    int* __restrict__ sorted)
{
    __shared__ int offs[NBINS];
    const int b = blockIdx.x, tid = threadIdx.x;
    for (int i = tid; i < NBINS; i += 1024)
        offs[i] = binstart[i] + colscanG[i * B1 + b];
    __syncthreads();
    const int e0 = b * EPB;
    for (int e = e0 + tid; e < e0 + EPB; e += 1024) {
        const int s = esrc[e], d = edst[e];
        const int p = atomicAdd(&offs[d >> 6], 1);
        sorted[p] = s | ((d & 63) << 17);
    }
}

// ---------------------------------------------------------------------------
// Per-layer scatter v2: block per 64-node bin. 8-deep batched pipeline:
// 8 coalesced sorted loads -> 8 independent scattered pin gathers (all in
// flight) -> 8 LDS atomics. Epilogue operands prefetched before the loop.
// ---------------------------------------------------------------------------
__global__ __launch_bounds__(256) void binned_scatter_kernel(
    const int* __restrict__ sorted, const int* __restrict__ binstart,
    const float* __restrict__ pin, const float* __restrict__ self_in,
    const float* __restrict__ wself_p, const float* __restrict__ bias_p,
    const float* __restrict__ wnext_p,
    float* __restrict__ h_out, float* __restrict__ p_next,
    const int* __restrict__ gid, float* __restrict__ out, int col)
{
    __shared__ float acc[4][64];
    const int b = blockIdx.x, tid = threadIdx.x;
    ((float*)acc)[tid] = 0.f;

    // hoist scalars + prefetch epilogue operands (land under the edge loop)
    const float sw    = wself_p ? *wself_p : 1.0f;
    const float bias  = *bias_p;
    const float wnext = wnext_p ? *wnext_p : 0.0f;
    const int   n     = b * 64 + tid;
    const bool  valid = (tid < 64) && (n < N_NODES);
    float selfv = 0.f;
    int   g     = 0;
    if (valid) { selfv = self_in[n]; g = gid[n]; }

    __syncthreads();

    const int st = binstart[b], en = binstart[b + 1];
    const int w = tid >> 6;
    int e = st + tid;

    // main: 8 edges per thread per iteration, batched issue
    for (; e + 1792 < en; e += 2048) {
        const int v0 = sorted[e];
        const int v1 = sorted[e + 256];
        const int v2 = sorted[e + 512];
        const int v3 = sorted[e + 768];
        const int v4 = sorted[e + 1024];
        const int v5 = sorted[e + 1280];
        const int v6 = sorted[e + 1536];
        const int v7 = sorted[e + 1792];
        const float f0 = pin[v0 & SRC_MASK];
        const float f1 = pin[v1 & SRC_MASK];
        const float f2 = pin[v2 & SRC_MASK];
        const float f3 = pin[v3 & SRC_MASK];
        const float f4 = pin[v4 & SRC_MASK];
        const float f5 = pin[v5 & SRC_MASK];
        const float f6 = pin[v6 & SRC_MASK];
        const float f7 = pin[v7 & SRC_MASK];
        atomicAdd(&acc[w][v0 >> 17], f0);
        atomicAdd(&acc[w][v1 >> 17], f1);
        atomicAdd(&acc[w][v2 >> 17], f2);
        atomicAdd(&acc[w][v3 >> 17], f3);
        atomicAdd(&acc[w][v4 >> 17], f4);
        atomicAdd(&acc[w][v5 >> 17], f5);
        atomicAdd(&acc[w][v6 >> 17], f6);
        atomicAdd(&acc[w][v7 >> 17], f7);
    }
    // tail
    for (; e < en; e += 256) {
        const int v = sorted[e];
        atomicAdd(&acc[w][v >> 17], pin[v & SRC_MASK]);
    }
    __syncthreads();

    if (tid < 64) {
        float h = 0.f;
        if (valid) {
            const float nb = acc[0][tid] + acc[1][tid] + acc[2][tid] + acc[3][tid];
            const float v = nb + bias + sw * selfv;
            h = v > 0.f ? v : 0.f;
            h_out[n] = h;
            if (wnext_p) p_next[n] = h * wnext;
        }
        const int g0 = __shfl(g, 0);
        if (__all(!valid || g == g0)) {
            float s = h;
            #pragma unroll
            for (int off = 32; off > 0; off >>= 1) s += __shfl_down(s, off);
            if (tid == 0) atomicAdd(&out[(size_t)g0 * N_COLS + col], s);
        } else if (valid) {
            atomicAdd(&out[(size_t)g * N_COLS + col], h);
        }
    }
}

extern "C" void kernel_launch(void* const* d_in, const int* in_sizes, int n_in,
                              void* d_out, int out_size, void* d_ws, size_t ws_size,
                              hipStream_t stream)
{
    (void)in_sizes; (void)n_in; (void)out_size; (void)ws_size;

    const float* x    = (const float*)d_in[0];
    const int*   esrc = (const int*)d_in[1];
    const int*   edst = (const int*)d_in[2];
    const int*   gid  = (const int*)d_in[3];
    const float* Wn0  = (const float*)d_in[4];
    const float* Ws0  = (const float*)d_in[5];
    const float* b0p  = (const float*)d_in[6];
    const float* Wnr  = (const float*)d_in[7];
    const float* Wsr  = (const float*)d_in[8];
    const float* brp  = (const float*)d_in[9];
    float* out = (float*)d_out;

    // workspace layout (16B-aligned first)
    float* pp    = (float*)d_ws;                         // NWAVES*2*512 floats
    float* bufP  = pp + (size_t)NWAVES * 2 * N_FEAT;
    float* bufP2 = bufP  + N_NODES;
    float* bufS  = bufP2 + N_NODES;
    float* bufH  = bufS  + N_NODES;
    int*   pt       = (int*)(bufH + N_NODES);            // NWAVES*2
    int*   starts   = pt + NWAVES * 2;                   // 65
    int*   binstart = starts + (N_GRAPHS + 1);           // NBINS+1
    int*   totalG   = binstart + NBINS + 1;              // NBINS
    int*   histG    = totalG + NBINS;                    // NBINS*B1
    int*   colscanG = histG + (size_t)NBINS * B1;        // NBINS*B1
    int*   sorted   = colscanG + (size_t)NBINS * B1;     // N_EDGES

    prep_kernel<<<B1, 1024, 0, stream>>>(edst, gid, histG, starts, out);
    pass_x_kernel<<<NWAVES / 4, 256, 0, stream>>>(
        x, gid, Wn0, Ws0, bufP, bufS, out, pp, pt);
    colscan_kernel<<<NBINS, 256, 0, stream>>>(histG, colscanG, totalG);
    scan2_kernel<<<1, 256, 0, stream>>>(totalG, binstart);
    reorder_kernel<<<B1, 1024, 0, stream>>>(esrc, edst, binstart, colscanG, sorted);
    reduce_x_kernel<<<N_GRAPHS, 512, 0, stream>>>(pp, pt, starts, out);

    binned_scatter_kernel<<<NBINS, 256, 0, stream>>>(
        sorted, binstart, bufP, bufS, nullptr, b0p, Wnr + 0, bufH, bufP2, gid, out, 512);
    binned_scatter_kernel<<<NBINS, 256, 0, stream>>>(
        sorted, binstart, bufP2, bufH, Wsr + 0, brp + 0, Wnr + 1, bufH, bufP, gid, out, 513);
    binned_scatter_kernel<<<NBINS, 256, 0, stream>>>(
        sorted, binstart, bufP, bufH, Wsr + 1, brp + 1, Wnr + 2, bufH, bufP2, gid, out, 514);
    binned_scatter_kernel<<<NBINS, 256, 0, stream>>>(
        sorted, binstart, bufP2, bufH, Wsr + 2, brp + 2, nullptr, bufH, nullptr, gid, out, 515);
}